// Round 7
// baseline (466.813 us; speedup 1.0000x reference)
//
#include <hip/hip_runtime.h>

typedef unsigned short u16;
typedef unsigned int   u32;
typedef __attribute__((ext_vector_type(8))) short bf16x8;
typedef __attribute__((ext_vector_type(4))) float f32x4;
typedef __attribute__((ext_vector_type(2))) float f32x2;

#define NFEAT  256
#define NBATCH 8192
#define BT     64    // batch tile per iteration
#define NBT    (NBATCH / BT)   // 128
#define ITERS  8     // bt-iterations per persistent block

__device__ __forceinline__ u16 f2bf(float f) {
    u32 u = __builtin_bit_cast(u32, f);
    return (u16)((u + 0x7FFFu + ((u >> 16) & 1u)) >> 16);
}
__device__ __forceinline__ u32 cvtpk(float a, float b) {
    u32 r;
    asm("v_cvt_pk_bf16_f32 %0, %1, %2" : "=v"(r) : "v"(a), "v"(b));
    return r;   // lo16 = bf16(a), hi16 = bf16(b), RNE
}
__device__ __forceinline__ f32x4 mfma16(bf16x8 a, bf16x8 b, f32x4 c) {
    return __builtin_amdgcn_mfma_f32_16x16x32_bf16(a, b, c, 0, 0, 0);
}
__device__ __forceinline__ bf16x8 frag_word0(u32 word0) {
    union { bf16x8 v; u32 w[4]; } u;
    u.w[0] = word0; u.w[1] = 0; u.w[2] = 0; u.w[3] = 0;
    return u.v;
}
// conflict-free LDS addressing: 256B rows, 4-bit slot swizzle (bijective)
__device__ __forceinline__ char* swz(char* base, int b, int col2) {
    return base + b * 256 + (col2 ^ ((b & 15) << 4));
}
__device__ __forceinline__ const char* swz(const char* base, int b, int col2) {
    return base + b * 256 + (col2 ^ ((b & 15) << 4));
}
// bias + relu + pack (pairwise; compiler may fuse to v_pk_add_f32)
__device__ __forceinline__ u32 relu_pk(float v0, float v1, float b0, float b1) {
    return cvtpk(fmaxf(v0 + b0, 0.f), fmaxf(v1 + b1, 0.f));
}

// ---------------------------------------------------------------------------
// prep: w0[f,o] = g_in[f,o] * sign(v_in[f,o,0])
// ---------------------------------------------------------------------------
__global__ void prep_w0(const float* __restrict__ v_in, const float* __restrict__ g_in,
                        u16* __restrict__ w0) {
    int i = blockIdx.x * blockDim.x + threadIdx.x;   // < 32768
    float v = v_in[i];
    float g = g_in[i];
    w0[i] = f2bf(v >= 0.f ? g : -g);
}

// ---------------------------------------------------------------------------
// prep: weight-normalize v_h0/v_h1/v_out rows -> bf16.  One wave per row.
// ---------------------------------------------------------------------------
__global__ void prep_norm(const float* __restrict__ v_h0, const float* __restrict__ g_h0,
                          const float* __restrict__ v_h1, const float* __restrict__ g_h1,
                          const float* __restrict__ v_out, const float* __restrict__ g_out,
                          u16* __restrict__ w1, u16* __restrict__ w2, u16* __restrict__ w3) {
    const int wave = (blockIdx.x * blockDim.x + threadIdx.x) >> 6;
    const int lane = threadIdx.x & 63;
    if (wave < 32768 + 16384) {
        const float* src; u16* dst; float g;
        if (wave < 32768) {
            src = v_h0 + (size_t)wave * 128; dst = w1 + (size_t)wave * 128; g = g_h0[wave];
        } else {
            int r = wave - 32768;
            src = v_h1 + (size_t)r * 128; dst = w2 + (size_t)r * 128; g = g_h1[r];
        }
        f32x2 v = *(const f32x2*)(src + lane * 2);
        float ss = v[0] * v[0] + v[1] * v[1];
        #pragma unroll
        for (int off = 32; off; off >>= 1) ss += __shfl_xor(ss, off);
        float s = g * rsqrtf(ss);
        *(u32*)(dst + lane * 2) = cvtpk(v[0] * s, v[1] * s);
    } else {
        int r = wave - 49152;   // < 4096
        const float* src = v_out + (size_t)r * 64;
        float v = src[lane];
        float ss = v * v;
        #pragma unroll
        for (int off = 32; off; off >>= 1) ss += __shfl_xor(ss, off);
        float s = g_out[r] * rsqrtf(ss);
        w3[(size_t)r * 64 + lane] = f2bf(v * s);
    }
}

// ---------------------------------------------------------------------------
// prep: x_t[f][b] = bf16( tab[b,0,f] * (1 - tab[b,1,f]) )   (64x64 LDS transpose)
// ---------------------------------------------------------------------------
__global__ void prep_x(const float* __restrict__ tab, u16* __restrict__ x_t) {
    __shared__ u16 tile[64][65];
    const int bb = (blockIdx.x % (NBATCH / 64)) * 64;
    const int ff = (blockIdx.x / (NBATCH / 64)) * 64;
    const int tr = threadIdx.x >> 6;    // 0..3
    const int tc = threadIdx.x & 63;
    #pragma unroll
    for (int i = 0; i < 16; i++) {
        int b = bb + tr + i * 4;
        float val  = tab[(size_t)b * 512 + ff + tc];
        float miss = tab[(size_t)b * 512 + 256 + ff + tc];
        tile[tr + i * 4][tc] = f2bf(val * (1.f - miss));
    }
    __syncthreads();
    #pragma unroll
    for (int i = 0; i < 16; i++) {
        int fr = tr + i * 4;
        x_t[(size_t)(ff + fr) * NBATCH + bb + tc] = tile[tc][fr];
    }
}

// ---------------------------------------------------------------------------
// logits[b][j] = bias[j] + sum_f outputs[b][f][j]
// ---------------------------------------------------------------------------
__global__ void reduce_logits(const float* __restrict__ outputs,
                              const float* __restrict__ bias,
                              float* __restrict__ logits) {
    const int b = blockIdx.x * 4 + (threadIdx.x >> 6);
    const int lane = threadIdx.x & 63;
    const int j4 = lane & 3;     // output quad
    const int fo = lane >> 2;    // feature offset 0..15
    const float* base = outputs + (size_t)b * (NFEAT * 16);
    f32x4 acc = {};
    #pragma unroll
    for (int it = 0; it < 16; it++) {
        f32x4 v = *(const f32x4*)(base + (fo + it * 16) * 16 + j4 * 4);
        acc[0] += v[0]; acc[1] += v[1]; acc[2] += v[2]; acc[3] += v[3];
    }
    #pragma unroll
    for (int off = 4; off < 64; off <<= 1) {
        acc[0] += __shfl_xor(acc[0], off);
        acc[1] += __shfl_xor(acc[1], off);
        acc[2] += __shfl_xor(acc[2], off);
        acc[3] += __shfl_xor(acc[3], off);
    }
    if (lane < 4) {
        f32x4 bs = *(const f32x4*)(bias + lane * 4);
        acc[0] += bs[0]; acc[1] += bs[1]; acc[2] += bs[2]; acc[3] += bs[3];
        *(f32x4*)(logits + b * 16 + lane * 4) = acc;
    }
}

// ---------------------------------------------------------------------------
// main: persistent-f blocks, 2 waves, register-dieted for >=3 waves/SIMD.
// Persistent regs: w2f (32) + a0pk (4).  W1 streamed per-ks from L2 with
// double-buffered prefetch; w3/biases streamed at point of use.
// Per iter: L0 rank-2 MFMA -> hA, L1 -> hB, L2 -> hA, L3 -> global.
// LDS: conflict-free 4-bit swizzle, 256B rows.  32KB/block -> 5 blocks/CU.
// ---------------------------------------------------------------------------
__global__ __launch_bounds__(128, 3) void nam_main(
    const u16* __restrict__ x_t, const u16* __restrict__ w0g,
    const u16* __restrict__ w1g, const u16* __restrict__ w2g, const u16* __restrict__ w3g,
    const float* __restrict__ b_in, const float* __restrict__ b_h0, const float* __restrict__ b_h1,
    float* __restrict__ outputs)
{
    __shared__ u16 hA[BT * 128];   // h0 (64 x 256B rows), later h2
    __shared__ u16 hB[BT * 128];   // h1 (64 x 256B rows)

    const int bid   = blockIdx.x;
    const int f     = (bid & 7) * 32 + ((bid >> 3) & 31);  // XCD-contiguous features
    const int chunk = bid >> 8;                            // 0..15
    const int t  = threadIdx.x;
    const int w  = t >> 6;          // 0..1 (o-half)
    const int lane = t & 63;
    const int lo = lane & 15;
    const int hi = lane >> 4;

    // ---- persistent per-feature state (kept tiny) ----
    u32 a0pk[4];                    // {w0, bf16(b_in)} packed, per m
    #pragma unroll
    for (int m = 0; m < 4; m++) {
        const int o = f * 128 + w * 64 + m * 16 + lo;
        float bi = b_in[o];
        a0pk[m] = (u32)w0g[o] | (cvtpk(bi, bi) << 16);
    }
    bf16x8 w2f[2][4];               // o = w*32 + m*16 + lo, k = ks*32 + hi*8
    {
        const u16* base = w2g + ((size_t)(f * 64 + w * 32 + lo)) * 128 + hi * 8;
        #pragma unroll
        for (int m = 0; m < 2; m++)
            #pragma unroll
            for (int ks = 0; ks < 4; ks++)
                w2f[m][ks] = *(const bf16x8*)(base + m * 16 * 128 + ks * 32);
    }
    const u16* w1base = w1g + ((size_t)(f * 128 + w * 64 + lo)) * 128 + hi * 8;
    const u16* w3base = w3g + ((size_t)(f * 16 + lo)) * 64 + hi * 8;

    for (int it = 0; it < ITERS; it++) {
        const int bt = chunk * ITERS + it;

        // layer-0 inputs + W1 ks=0 prefetch (overlap prev L3 + barrier + L0)
        u32 xw[4];
        #pragma unroll
        for (int n = 0; n < 4; n++)
            xw[n] = (u32)x_t[(size_t)f * NBATCH + bt * BT + n * 16 + lo];
        bf16x8 wc[4];
        #pragma unroll
        for (int m = 0; m < 4; m++)
            wc[m] = *(const bf16x8*)(w1base + m * 2048);

        __syncthreads();   // prev iter's L3 reads of hA complete

        // ---------- layer 0 (rank-2 MFMA): h0[o][b] = relu(w0[o]*x[b]+b_in[o])
        {
            bf16x8 bm[4];
            #pragma unroll
            for (int n = 0; n < 4; n++)
                bm[n] = frag_word0(hi == 0 ? (xw[n] | 0x3F800000u) : 0u);
            #pragma unroll
            for (int m = 0; m < 4; m++) {
                bf16x8 a0 = frag_word0(hi == 0 ? a0pk[m] : 0u);
                #pragma unroll
                for (int n = 0; n < 4; n++) {
                    f32x4 d = mfma16(a0, bm[n], f32x4{});
                    const int b = n * 16 + lo;
                    const int col2 = (w * 64 + m * 16 + hi * 4) * 2;
                    *(uint2*)swz((char*)hA, b, col2) =
                        make_uint2(cvtpk(fmaxf(0.f, d[0]), fmaxf(0.f, d[1])),
                                   cvtpk(fmaxf(0.f, d[2]), fmaxf(0.f, d[3])));
                }
            }
        }
        __syncthreads();

        // ---------- layer 1: h1 = relu(W1 (128x128) . h0^T + b_h0) ----------
        // W1 streamed per-ks, double-buffered (wc -> wn)
        {
            f32x4 acc[4][4] = {};
            #pragma unroll
            for (int ks = 0; ks < 4; ks++) {
                bf16x8 wn[4];
                if (ks < 3) {
                    #pragma unroll
                    for (int m = 0; m < 4; m++)
                        wn[m] = *(const bf16x8*)(w1base + m * 2048 + (ks + 1) * 32);
                }
                bf16x8 bm[4];
                #pragma unroll
                for (int n = 0; n < 4; n++) {
                    const int b = n * 16 + lo;
                    bm[n] = *(const bf16x8*)swz((const char*)hA, b, ks * 64 + hi * 16);
                }
                __builtin_amdgcn_s_setprio(1);
                #pragma unroll
                for (int m = 0; m < 4; m++)
                    #pragma unroll
                    for (int n = 0; n < 4; n++)
                        acc[m][n] = mfma16(wc[m], bm[n], acc[m][n]);
                __builtin_amdgcn_s_setprio(0);
                if (ks < 3) {
                    #pragma unroll
                    for (int m = 0; m < 4; m++) wc[m] = wn[m];
                }
            }
            #pragma unroll
            for (int m = 0; m < 4; m++) {
                f32x4 bs = *(const f32x4*)(b_h0 + f * 128 + w * 64 + m * 16 + hi * 4);
                const int col2 = (w * 64 + m * 16 + hi * 4) * 2;
                #pragma unroll
                for (int n = 0; n < 4; n++) {
                    const int b = n * 16 + lo;
                    u32 p0 = relu_pk(acc[m][n][0], acc[m][n][1], bs[0], bs[1]);
                    u32 p1 = relu_pk(acc[m][n][2], acc[m][n][3], bs[2], bs[3]);
                    *(uint2*)swz((char*)hB, b, col2) = make_uint2(p0, p1);
                }
            }
        }
        __syncthreads();

        // ---------- layer 2: h2 = relu(W2 (64x128) . h1^T + b_h1) -----------
        // h2 -> hA, 256B-stride rows; w3 prefetched here for L3
        bf16x8 w3a, w3b;
        {
            w3a = *(const bf16x8*)(w3base);
            w3b = *(const bf16x8*)(w3base + 32);
            f32x4 acc[2][4] = {};
            #pragma unroll
            for (int ks = 0; ks < 4; ks++) {
                bf16x8 bm[4];
                #pragma unroll
                for (int n = 0; n < 4; n++) {
                    const int b = n * 16 + lo;
                    bm[n] = *(const bf16x8*)swz((const char*)hB, b, ks * 64 + hi * 16);
                }
                __builtin_amdgcn_s_setprio(1);
                #pragma unroll
                for (int m = 0; m < 2; m++)
                    #pragma unroll
                    for (int n = 0; n < 4; n++)
                        acc[m][n] = mfma16(w2f[m][ks], bm[n], acc[m][n]);
                __builtin_amdgcn_s_setprio(0);
            }
            #pragma unroll
            for (int m = 0; m < 2; m++) {
                f32x4 bs = *(const f32x4*)(b_h1 + f * 64 + w * 32 + m * 16 + hi * 4);
                const int col2 = (w * 32 + m * 16 + hi * 4) * 2;
                #pragma unroll
                for (int n = 0; n < 4; n++) {
                    const int b = n * 16 + lo;
                    u32 p0 = relu_pk(acc[m][n][0], acc[m][n][1], bs[0], bs[1]);
                    u32 p1 = relu_pk(acc[m][n][2], acc[m][n][3], bs[2], bs[3]);
                    *(uint2*)swz((char*)hA, b, col2) = make_uint2(p0, p1);
                }
            }
        }
        __syncthreads();

        // ---------- layer 3: out = W3 (16x64) . h2^T ------------------------
        {
            f32x4 acc[2] = {};
            #pragma unroll
            for (int ks = 0; ks < 2; ks++) {
                bf16x8 a = (ks == 0) ? w3a : w3b;
                #pragma unroll
                for (int n = 0; n < 2; n++) {
                    const int b = w * 32 + n * 16 + lo;
                    bf16x8 bm = *(const bf16x8*)swz((const char*)hA, b, ks * 64 + hi * 16);
                    acc[n] = mfma16(a, bm, acc[n]);
                }
            }
            #pragma unroll
            for (int n = 0; n < 2; n++) {
                const int gb = bt * BT + w * 32 + n * 16 + lo;   // global batch row
                float* op = outputs + ((size_t)gb * NFEAT + f) * 16 + hi * 4;
                *(f32x4*)op = acc[n];
            }
        }
    }
}

// ---------------------------------------------------------------------------
extern "C" void kernel_launch(void* const* d_in, const int* in_sizes, int n_in,
                              void* d_out, int out_size, void* d_ws, size_t ws_size,
                              hipStream_t stream) {
    const float* tab   = (const float*)d_in[0];
    const float* v_in  = (const float*)d_in[1];
    const float* g_in  = (const float*)d_in[2];
    const float* b_in  = (const float*)d_in[3];
    const float* v_h0  = (const float*)d_in[4];
    const float* g_h0  = (const float*)d_in[5];
    const float* b_h0  = (const float*)d_in[6];
    const float* v_h1  = (const float*)d_in[7];
    const float* g_h1  = (const float*)d_in[8];
    const float* b_h1  = (const float*)d_in[9];
    const float* v_out = (const float*)d_in[10];
    const float* g_out = (const float*)d_in[11];
    const float* bias  = (const float*)d_in[12];

    char* ws = (char*)d_ws;
    u16* w0  = (u16*)(ws);                         //  32768 * 2
    u16* w1  = (u16*)(ws + 65536);                 // 4194304 * 2
    u16* w2  = (u16*)(ws + 65536 + 8388608);       // 2097152 * 2
    u16* w3  = (u16*)(ws + 12648448);              //  262144 * 2
    u16* x_t = (u16*)(ws + 13172736);              // 2097152 * 2  (end ~17.4MB)

    float* logits  = (float*)d_out;
    float* outputs = (float*)d_out + (size_t)NBATCH * 16;

    hipLaunchKernelGGL(prep_w0,   dim3(128),   dim3(256), 0, stream, v_in, g_in, w0);
    hipLaunchKernelGGL(prep_norm, dim3(13312), dim3(256), 0, stream,
                       v_h0, g_h0, v_h1, g_h1, v_out, g_out, w1, w2, w3);
    hipLaunchKernelGGL(prep_x,    dim3(512),   dim3(256), 0, stream, tab, x_t);
    hipLaunchKernelGGL(nam_main,  dim3(NFEAT * NBT / ITERS), dim3(128), 0, stream,
                       x_t, w0, w1, w2, w3, b_in, b_h0, b_h1, outputs);
    hipLaunchKernelGGL(reduce_logits, dim3(NBATCH / 4), dim3(256), 0, stream,
                       outputs, bias, logits);
}

// Round 8
// 176.846 us; speedup vs baseline: 2.6397x; 2.6397x over previous
//
#include <hip/hip_runtime.h>

typedef unsigned short u16;
typedef unsigned int   u32;
typedef __attribute__((ext_vector_type(8))) short bf16x8;
typedef __attribute__((ext_vector_type(4))) float f32x4;
typedef __attribute__((ext_vector_type(2))) float f32x2;

#define NFEAT  256
#define NBATCH 8192
#define BT     128   // batch tile per iteration (4 waves: 2 o-halves x 2 b-halves)
#define NBT    (NBATCH / BT)   // 64
#define ITERS  8     // bt-iterations per persistent block -> grid 2048

__device__ __forceinline__ u16 f2bf(float f) {
    u32 u = __builtin_bit_cast(u32, f);
    return (u16)((u + 0x7FFFu + ((u >> 16) & 1u)) >> 16);
}
__device__ __forceinline__ u32 cvtpk(float a, float b) {
    u32 r;
    asm("v_cvt_pk_bf16_f32 %0, %1, %2" : "=v"(r) : "v"(a), "v"(b));
    return r;   // lo16 = bf16(a), hi16 = bf16(b), RNE
}
__device__ __forceinline__ f32x4 mfma16(bf16x8 a, bf16x8 b, f32x4 c) {
    return __builtin_amdgcn_mfma_f32_16x16x32_bf16(a, b, c, 0, 0, 0);
}
__device__ __forceinline__ bf16x8 frag_word0(u32 word0) {
    union { bf16x8 v; u32 w[4]; } u;
    u.w[0] = word0; u.w[1] = 0; u.w[2] = 0; u.w[3] = 0;
    return u.v;
}
// conflict-free LDS addressing: 256B rows, 4-bit slot swizzle (bijective)
__device__ __forceinline__ char* swz(char* base, int b, int col2) {
    return base + b * 256 + (col2 ^ ((b & 15) << 4));
}
__device__ __forceinline__ const char* swz(const char* base, int b, int col2) {
    return base + b * 256 + (col2 ^ ((b & 15) << 4));
}
// bias + relu + pack
__device__ __forceinline__ u32 relu_pk(float v0, float v1, float b0, float b1) {
    return cvtpk(fmaxf(v0 + b0, 0.f), fmaxf(v1 + b1, 0.f));
}

// ---------------------------------------------------------------------------
// prep: w0[f,o] = g_in[f,o] * sign(v_in[f,o,0])
// ---------------------------------------------------------------------------
__global__ void prep_w0(const float* __restrict__ v_in, const float* __restrict__ g_in,
                        u16* __restrict__ w0) {
    int i = blockIdx.x * blockDim.x + threadIdx.x;   // < 32768
    float v = v_in[i];
    float g = g_in[i];
    w0[i] = f2bf(v >= 0.f ? g : -g);
}

// ---------------------------------------------------------------------------
// prep: weight-normalize v_h0/v_h1/v_out rows -> bf16.  One wave per row.
// ---------------------------------------------------------------------------
__global__ void prep_norm(const float* __restrict__ v_h0, const float* __restrict__ g_h0,
                          const float* __restrict__ v_h1, const float* __restrict__ g_h1,
                          const float* __restrict__ v_out, const float* __restrict__ g_out,
                          u16* __restrict__ w1, u16* __restrict__ w2, u16* __restrict__ w3) {
    const int wave = (blockIdx.x * blockDim.x + threadIdx.x) >> 6;
    const int lane = threadIdx.x & 63;
    if (wave < 32768 + 16384) {
        const float* src; u16* dst; float g;
        if (wave < 32768) {
            src = v_h0 + (size_t)wave * 128; dst = w1 + (size_t)wave * 128; g = g_h0[wave];
        } else {
            int r = wave - 32768;
            src = v_h1 + (size_t)r * 128; dst = w2 + (size_t)r * 128; g = g_h1[r];
        }
        f32x2 v = *(const f32x2*)(src + lane * 2);
        float ss = v[0] * v[0] + v[1] * v[1];
        #pragma unroll
        for (int off = 32; off; off >>= 1) ss += __shfl_xor(ss, off);
        float s = g * rsqrtf(ss);
        *(u32*)(dst + lane * 2) = cvtpk(v[0] * s, v[1] * s);
    } else {
        int r = wave - 49152;   // < 4096
        const float* src = v_out + (size_t)r * 64;
        float v = src[lane];
        float ss = v * v;
        #pragma unroll
        for (int off = 32; off; off >>= 1) ss += __shfl_xor(ss, off);
        float s = g_out[r] * rsqrtf(ss);
        w3[(size_t)r * 64 + lane] = f2bf(v * s);
    }
}

// ---------------------------------------------------------------------------
// prep: x_t[f][b] = bf16( tab[b,0,f] * (1 - tab[b,1,f]) )   (64x64 LDS transpose)
// ---------------------------------------------------------------------------
__global__ void prep_x(const float* __restrict__ tab, u16* __restrict__ x_t) {
    __shared__ u16 tile[64][65];
    const int bb = (blockIdx.x % (NBATCH / 64)) * 64;
    const int ff = (blockIdx.x / (NBATCH / 64)) * 64;
    const int tr = threadIdx.x >> 6;    // 0..3
    const int tc = threadIdx.x & 63;
    #pragma unroll
    for (int i = 0; i < 16; i++) {
        int b = bb + tr + i * 4;
        float val  = tab[(size_t)b * 512 + ff + tc];
        float miss = tab[(size_t)b * 512 + 256 + ff + tc];
        tile[tr + i * 4][tc] = f2bf(val * (1.f - miss));
    }
    __syncthreads();
    #pragma unroll
    for (int i = 0; i < 16; i++) {
        int fr = tr + i * 4;
        x_t[(size_t)(ff + fr) * NBATCH + bb + tc] = tile[tc][fr];
    }
}

// ---------------------------------------------------------------------------
// logits[b][j] = bias[j] + sum_f outputs[b][f][j]
// ---------------------------------------------------------------------------
__global__ void reduce_logits(const float* __restrict__ outputs,
                              const float* __restrict__ bias,
                              float* __restrict__ logits) {
    const int b = blockIdx.x * 4 + (threadIdx.x >> 6);
    const int lane = threadIdx.x & 63;
    const int j4 = lane & 3;     // output quad
    const int fo = lane >> 2;    // feature offset 0..15
    const float* base = outputs + (size_t)b * (NFEAT * 16);
    f32x4 acc = {};
    #pragma unroll
    for (int it = 0; it < 16; it++) {
        f32x4 v = *(const f32x4*)(base + (fo + it * 16) * 16 + j4 * 4);
        acc[0] += v[0]; acc[1] += v[1]; acc[2] += v[2]; acc[3] += v[3];
    }
    #pragma unroll
    for (int off = 4; off < 64; off <<= 1) {
        acc[0] += __shfl_xor(acc[0], off);
        acc[1] += __shfl_xor(acc[1], off);
        acc[2] += __shfl_xor(acc[2], off);
        acc[3] += __shfl_xor(acc[3], off);
    }
    if (lane < 4) {
        f32x4 bs = *(const f32x4*)(bias + lane * 4);
        acc[0] += bs[0]; acc[1] += bs[1]; acc[2] += bs[2]; acc[3] += bs[3];
        *(f32x4*)(logits + b * 16 + lane * 4) = acc;
    }
}

// ---------------------------------------------------------------------------
// main: persistent-f blocks, 256 thr = 4 waves (wo x wb = 2x2), BT=128.
// Each wave has R5's proven per-wave register structure (acc[4][4], w1f[4][4],
// w2f, w3f, biases all persistent — no in-loop weight streaming, no spill),
// but a block covers 2x the batches -> per-batch LDS traffic, weight re-reads
// and barriers HALVED.  LDS 64KB -> 2 blocks/CU (8 waves).
// Per iter: L0 rank-2 MFMA -> hA, L1 -> hB, L2 -> hA, L3 -> global.
// LDS: conflict-free 4-bit swizzle, 256B rows.
// ---------------------------------------------------------------------------
__global__ __launch_bounds__(256, 2) void nam_main(
    const u16* __restrict__ x_t, const u16* __restrict__ w0g,
    const u16* __restrict__ w1g, const u16* __restrict__ w2g, const u16* __restrict__ w3g,
    const float* __restrict__ b_in, const float* __restrict__ b_h0, const float* __restrict__ b_h1,
    float* __restrict__ outputs)
{
    __shared__ u16 hA[BT * 128];   // h0 (128 x 256B rows), later h2
    __shared__ u16 hB[BT * 128];   // h1 (128 x 256B rows)

    const int bid   = blockIdx.x;
    const int f     = (bid & 7) * 32 + ((bid >> 3) & 31);  // XCD-contiguous features
    const int chunk = bid >> 8;                            // 0..7
    const int t  = threadIdx.x;
    const int w  = t >> 6;          // 0..3
    const int wo = w >> 1;          // o-half
    const int wb = w & 1;           // b-half
    const int lane = t & 63;
    const int lo = lane & 15;
    const int hi = lane >> 4;

    // ---- persistent per-feature state (identical per-wave shape to R5) ----
    u32 a0pk[4];                    // {w0, bf16(b_in)} packed, o = wo*64+m*16+lo
    #pragma unroll
    for (int m = 0; m < 4; m++) {
        const int o = f * 128 + wo * 64 + m * 16 + lo;
        float bi = b_in[o];
        a0pk[m] = (u32)w0g[o] | (cvtpk(bi, bi) << 16);
    }
    bf16x8 w1f[4][4];   // o = wo*64 + m*16 + lo, k = ks*32 + hi*8
    {
        const u16* base = w1g + ((size_t)(f * 128 + wo * 64 + lo)) * 128 + hi * 8;
        #pragma unroll
        for (int m = 0; m < 4; m++)
            #pragma unroll
            for (int ks = 0; ks < 4; ks++)
                w1f[m][ks] = *(const bf16x8*)(base + m * 2048 + ks * 32);
    }
    bf16x8 w2f[2][4];   // o = wo*32 + m*16 + lo
    {
        const u16* base = w2g + ((size_t)(f * 64 + wo * 32 + lo)) * 128 + hi * 8;
        #pragma unroll
        for (int m = 0; m < 2; m++)
            #pragma unroll
            for (int ks = 0; ks < 4; ks++)
                w2f[m][ks] = *(const bf16x8*)(base + m * 2048 + ks * 32);
    }
    bf16x8 w3f[2];      // o = lo (16 rows)
    {
        const u16* base = w3g + ((size_t)(f * 16 + lo)) * 64 + hi * 8;
        #pragma unroll
        for (int ks = 0; ks < 2; ks++)
            w3f[ks] = *(const bf16x8*)(base + ks * 32);
    }
    f32x4 bs1[4];   // b_h0 for ob = wo*64 + m*16 + hi*4
    #pragma unroll
    for (int m = 0; m < 4; m++)
        bs1[m] = *(const f32x4*)(b_h0 + f * 128 + wo * 64 + m * 16 + hi * 4);
    f32x4 bs2[2];   // b_h1 for ob = wo*32 + m*16 + hi*4
    #pragma unroll
    for (int m = 0; m < 2; m++)
        bs2[m] = *(const f32x4*)(b_h1 + f * 64 + wo * 32 + m * 16 + hi * 4);

    for (int it = 0; it < ITERS; it++) {
        const int bt = chunk * ITERS + it;

        // layer-0 inputs for this tile (b-half of this wave)
        u32 xw[4];
        #pragma unroll
        for (int n = 0; n < 4; n++)
            xw[n] = (u32)x_t[(size_t)f * NBATCH + bt * BT + wb * 64 + n * 16 + lo];

        __syncthreads();   // prev iter's L3 reads of hA complete

        // ---------- layer 0 (rank-2 MFMA): h0[o][b] = relu(w0[o]*x[b]+b_in[o])
        {
            bf16x8 bm[4];
            #pragma unroll
            for (int n = 0; n < 4; n++)
                bm[n] = frag_word0(hi == 0 ? (xw[n] | 0x3F800000u) : 0u);
            #pragma unroll
            for (int m = 0; m < 4; m++) {
                bf16x8 a0 = frag_word0(hi == 0 ? a0pk[m] : 0u);
                #pragma unroll
                for (int n = 0; n < 4; n++) {
                    f32x4 d = mfma16(a0, bm[n], f32x4{});
                    const int b = wb * 64 + n * 16 + lo;
                    const int col2 = (wo * 64 + m * 16 + hi * 4) * 2;
                    *(uint2*)swz((char*)hA, b, col2) =
                        make_uint2(cvtpk(fmaxf(0.f, d[0]), fmaxf(0.f, d[1])),
                                   cvtpk(fmaxf(0.f, d[2]), fmaxf(0.f, d[3])));
                }
            }
        }
        __syncthreads();

        // ---------- layer 1: h1 = relu(W1 (128x128) . h0^T + b_h0) ----------
        {
            f32x4 acc[4][4] = {};
            #pragma unroll
            for (int ks = 0; ks < 4; ks++) {
                bf16x8 bm[4];
                #pragma unroll
                for (int n = 0; n < 4; n++) {
                    const int b = wb * 64 + n * 16 + lo;
                    bm[n] = *(const bf16x8*)swz((const char*)hA, b, ks * 64 + hi * 16);
                }
                __builtin_amdgcn_s_setprio(1);
                #pragma unroll
                for (int m = 0; m < 4; m++)
                    #pragma unroll
                    for (int n = 0; n < 4; n++)
                        acc[m][n] = mfma16(w1f[m][ks], bm[n], acc[m][n]);
                __builtin_amdgcn_s_setprio(0);
            }
            #pragma unroll
            for (int m = 0; m < 4; m++) {
                const int col2 = (wo * 64 + m * 16 + hi * 4) * 2;
                #pragma unroll
                for (int n = 0; n < 4; n++) {
                    const int b = wb * 64 + n * 16 + lo;
                    u32 p0 = relu_pk(acc[m][n][0], acc[m][n][1], bs1[m][0], bs1[m][1]);
                    u32 p1 = relu_pk(acc[m][n][2], acc[m][n][3], bs1[m][2], bs1[m][3]);
                    *(uint2*)swz((char*)hB, b, col2) = make_uint2(p0, p1);
                }
            }
        }
        __syncthreads();

        // ---------- layer 2: h2 = relu(W2 (64x128) . h1^T + b_h1) -----------
        // h2 -> hA, 256B-stride rows (cols 0..127 bytes used)
        {
            f32x4 acc[2][4] = {};
            #pragma unroll
            for (int ks = 0; ks < 4; ks++) {
                bf16x8 bm[4];
                #pragma unroll
                for (int n = 0; n < 4; n++) {
                    const int b = wb * 64 + n * 16 + lo;
                    bm[n] = *(const bf16x8*)swz((const char*)hB, b, ks * 64 + hi * 16);
                }
                __builtin_amdgcn_s_setprio(1);
                #pragma unroll
                for (int m = 0; m < 2; m++)
                    #pragma unroll
                    for (int n = 0; n < 4; n++)
                        acc[m][n] = mfma16(w2f[m][ks], bm[n], acc[m][n]);
                __builtin_amdgcn_s_setprio(0);
            }
            #pragma unroll
            for (int m = 0; m < 2; m++) {
                const int col2 = (wo * 32 + m * 16 + hi * 4) * 2;
                #pragma unroll
                for (int n = 0; n < 4; n++) {
                    const int b = wb * 64 + n * 16 + lo;
                    u32 p0 = relu_pk(acc[m][n][0], acc[m][n][1], bs2[m][0], bs2[m][1]);
                    u32 p1 = relu_pk(acc[m][n][2], acc[m][n][3], bs2[m][2], bs2[m][3]);
                    *(uint2*)swz((char*)hA, b, col2) = make_uint2(p0, p1);
                }
            }
        }
        __syncthreads();

        // ---------- layer 3: out = W3 (16x64) . h2^T ------------------------
        // 4 waves split b 4-ways: b = w*32 + n*16 + lo, n 0..1
        {
            f32x4 acc[2] = {};
            #pragma unroll
            for (int ks = 0; ks < 2; ks++) {
                #pragma unroll
                for (int n = 0; n < 2; n++) {
                    const int b = w * 32 + n * 16 + lo;
                    bf16x8 bm = *(const bf16x8*)swz((const char*)hA, b, ks * 64 + hi * 16);
                    acc[n] = mfma16(w3f[ks], bm, acc[n]);
                }
            }
            #pragma unroll
            for (int n = 0; n < 2; n++) {
                const int gb = bt * BT + w * 32 + n * 16 + lo;   // global batch row
                float* op = outputs + ((size_t)gb * NFEAT + f) * 16 + hi * 4;
                *(f32x4*)op = acc[n];
            }
        }
    }
}

// ---------------------------------------------------------------------------
extern "C" void kernel_launch(void* const* d_in, const int* in_sizes, int n_in,
                              void* d_out, int out_size, void* d_ws, size_t ws_size,
                              hipStream_t stream) {
    const float* tab   = (const float*)d_in[0];
    const float* v_in  = (const float*)d_in[1];
    const float* g_in  = (const float*)d_in[2];
    const float* b_in  = (const float*)d_in[3];
    const float* v_h0  = (const float*)d_in[4];
    const float* g_h0  = (const float*)d_in[5];
    const float* b_h0  = (const float*)d_in[6];
    const float* v_h1  = (const float*)d_in[7];
    const float* g_h1  = (const float*)d_in[8];
    const float* b_h1  = (const float*)d_in[9];
    const float* v_out = (const float*)d_in[10];
    const float* g_out = (const float*)d_in[11];
    const float* bias  = (const float*)d_in[12];

    char* ws = (char*)d_ws;
    u16* w0  = (u16*)(ws);                         //  32768 * 2
    u16* w1  = (u16*)(ws + 65536);                 // 4194304 * 2
    u16* w2  = (u16*)(ws + 65536 + 8388608);       // 2097152 * 2
    u16* w3  = (u16*)(ws + 12648448);              //  262144 * 2
    u16* x_t = (u16*)(ws + 13172736);              // 2097152 * 2  (end ~17.4MB)

    float* logits  = (float*)d_out;
    float* outputs = (float*)d_out + (size_t)NBATCH * 16;

    hipLaunchKernelGGL(prep_w0,   dim3(128),   dim3(256), 0, stream, v_in, g_in, w0);
    hipLaunchKernelGGL(prep_norm, dim3(13312), dim3(256), 0, stream,
                       v_h0, g_h0, v_h1, g_h1, v_out, g_out, w1, w2, w3);
    hipLaunchKernelGGL(prep_x,    dim3(512),   dim3(256), 0, stream, tab, x_t);
    hipLaunchKernelGGL(nam_main,  dim3(NFEAT * NBT / ITERS), dim3(256), 0, stream,
                       x_t, w0, w1, w2, w3, b_in, b_h0, b_h1, outputs);
    hipLaunchKernelGGL(reduce_logits, dim3(NBATCH / 4), dim3(256), 0, stream,
                       outputs, bias, logits);
}